// Round 1
// baseline (74.190 us; speedup 1.0000x reference)
//
#include <hip/hip_runtime.h>
#include <math.h>

// ---------------------------------------------------------------------------
// Quantum circuit collapses analytically:
//   state = v^{tensor4},  v = (RZ(f0)RY(f1))[:,0]
//   Bloch vector of v: x = sin f1 cos f0, y = sin f1 sin f0, z = cos f1
//   Z_exp = Tr(M rho^{tensor4}),  M = W^dag Z0 W (batch-independent, 16x16)
//         = degree-4 polynomial in (x,y,z): 35 monomial coefficients.
// Kernel 1 computes the coefficients (1 block); kernel 2 evaluates per batch.
// ---------------------------------------------------------------------------

struct cpx { float re, im; };

__device__ __forceinline__ cpx cmul(cpx a, cpx b) {
    return { a.re * b.re - a.im * b.im, a.re * b.im + a.im * b.re };
}
__device__ __forceinline__ cpx cadd(cpx a, cpx b) { return { a.re + b.re, a.im + b.im }; }

__device__ __forceinline__ void mm2(const cpx A[2][2], const cpx B[2][2], cpx C[2][2]) {
    #pragma unroll
    for (int r = 0; r < 2; ++r)
        #pragma unroll
        for (int c = 0; c < 2; ++c)
            C[r][c] = cadd(cmul(A[r][0], B[0][c]), cmul(A[r][1], B[1][c]));
}

__global__ __launch_bounds__(256) void precompute_coef(
    const float* __restrict__ w_U, const float* __restrict__ w_RXZX,
    float* __restrict__ coef /* 125 floats, index (a*5+b)*5+c */)
{
    __shared__ cpx W[16][16];   // the accumulated circuit unitary
    __shared__ cpx M[16][16];   // W^dag Z0 W
    __shared__ float cp[256];   // Pauli-basis coefficients

    const int tid = threadIdx.x;
    const int i = tid >> 4, j = tid & 15;   // (row, col) of W owned by this thread

    W[i][j] = { (i == j) ? 1.f : 0.f, 0.f };
    __syncthreads();

    // ISWAP_PAIRS = [(1,2),(1,3),(1,2),(1,3),(0,3),(0,2)]
    const int PP[6] = {1, 1, 1, 1, 0, 0};
    const int QQ[6] = {2, 3, 2, 3, 3, 2};

    for (int l = 0; l < 6; ++l) {
        // ---- iSWAP(w_U[l]) on (p,q): mixes states where bits p,q differ ----
        const int wp = 8 >> PP[l], wq = 8 >> QQ[l];
        const float t = w_U[l];
        const float ct = cosf(t), st = sinf(t);   // gate = [[c, i s],[i s, c]] on {|01>,|10>}
        const int bp = (i & wp) ? 1 : 0, bq = (i & wq) ? 1 : 0;
        cpx val;
        if (bp != bq) {
            cpx a = W[i][j], b = W[i ^ (wp | wq)][j];
            val.re = ct * a.re - st * b.im;   // c*a + (i*st)*b
            val.im = ct * a.im + st * b.re;
        } else {
            val = W[i][j];
        }
        __syncthreads();
        W[i][j] = val;
        __syncthreads();

        // ---- per-qubit RXZX(a,b,c) = RX(a) RZ(b) RX(c) ----
        for (int qb = 0; qb < 4; ++qb) {
            const float ta = w_RXZX[(l * 4 + qb) * 3 + 0];
            const float tb = w_RXZX[(l * 4 + qb) * 3 + 1];
            const float tc = w_RXZX[(l * 4 + qb) * 3 + 2];
            float sa, ca, sb, cb, sc, cc;
            sincosf(0.5f * ta, &sa, &ca);
            sincosf(0.5f * tb, &sb, &cb);
            sincosf(0.5f * tc, &sc, &cc);
            const cpx RXa[2][2] = { { {ca, 0.f}, {0.f, -sa} }, { {0.f, -sa}, {ca, 0.f} } };
            const cpx RZb[2][2] = { { {cb, -sb}, {0.f, 0.f} }, { {0.f, 0.f}, {cb, sb} } };
            const cpx RXc[2][2] = { { {cc, 0.f}, {0.f, -sc} }, { {0.f, -sc}, {cc, 0.f} } };
            cpx T1[2][2], g[2][2];
            mm2(RZb, RXc, T1);
            mm2(RXa, T1, g);

            const int w = 8 >> qb;
            const int b = (i & w) ? 1 : 0;
            cpx x0 = W[i & ~w][j], x1 = W[i | w][j];
            cpx v2 = cadd(cmul(g[b][0], x0), cmul(g[b][1], x1));
            __syncthreads();
            W[i][j] = v2;
            __syncthreads();
        }
    }

    // ---- M[i][j] = sum_k conj(W[k][i]) * z_k * W[k][j],  z_k = +1 (k<8) else -1
    cpx m = {0.f, 0.f};
    #pragma unroll
    for (int k = 0; k < 16; ++k) {
        const float zk = (k < 8) ? 1.f : -1.f;
        cpx a = W[k][i];
        cpx b = W[k][j];
        m.re += zk * (a.re * b.re + a.im * b.im);   // conj(a)*b
        m.im += zk * (a.re * b.im - a.im * b.re);
    }
    M[i][j] = m;          // M != W, no hazard
    __syncthreads();

    // ---- Pauli coefficient c_p = Tr(M * P_p)/16, p = tid, P = sx_{p0} x ... x s_{p3}
    // Each Pauli column has exactly one nonzero: c_p = (1/16) sum_col M[col][row(col)]*val(col)
    cpx acc = {0.f, 0.f};
    for (int col = 0; col < 16; ++col) {
        int row = 0;
        cpx val = {1.f, 0.f};
        #pragma unroll
        for (int k = 0; k < 4; ++k) {
            const int pk = (tid >> (6 - 2 * k)) & 3;   // pauli on qubit k (0=I,1=X,2=Y,3=Z)
            const int b = (col >> (3 - k)) & 1;
            int rb = b;
            if (pk == 1) {
                rb = b ^ 1;
            } else if (pk == 2) {
                rb = b ^ 1;
                cpx f = {0.f, b ? -1.f : 1.f};   // sy[1][0]=i, sy[0][1]=-i
                val = cmul(val, f);
            } else if (pk == 3) {
                if (b) { val.re = -val.re; val.im = -val.im; }
            }
            row |= rb << (3 - k);
        }
        acc = cadd(acc, cmul(M[col][row], val));
    }
    cp[tid] = acc.re * (1.f / 16.f);   // Hermitian => trace real
    __syncthreads();

    // ---- collapse 256 Pauli terms -> 35 monomials x^a y^b z^c (serial = deterministic)
    if (tid == 0) {
        float C[125];
        for (int t2 = 0; t2 < 125; ++t2) C[t2] = 0.f;
        for (int p = 0; p < 256; ++p) {
            int a = 0, b = 0, c = 0;
            #pragma unroll
            for (int k = 0; k < 4; ++k) {
                const int pk = (p >> (2 * k)) & 3;
                a += (pk == 1); b += (pk == 2); c += (pk == 3);
            }
            C[(a * 5 + b) * 5 + c] += cp[p];
        }
        for (int t2 = 0; t2 < 125; ++t2) coef[t2] = C[t2];
    }
}

__global__ __launch_bounds__(256) void eval_poly(
    const float2* __restrict__ in, const float* __restrict__ coef,
    const float* __restrict__ scale_p, const float* __restrict__ bias_p,
    float* __restrict__ out, int B)
{
    const int idx = blockIdx.x * blockDim.x + threadIdx.x;
    if (idx >= B) return;

    const float2 f = in[idx];
    float s0, c0, s1, c1;
    sincosf(f.x, &s0, &c0);
    sincosf(f.y, &s1, &c1);
    const float x = s1 * c0, y = s1 * s0, z = c1;

    float xp[5], yp[5], zp[5];
    xp[0] = yp[0] = zp[0] = 1.f;
    #pragma unroll
    for (int k = 1; k < 5; ++k) {
        xp[k] = xp[k - 1] * x;
        yp[k] = yp[k - 1] * y;
        zp[k] = zp[k - 1] * z;
    }

    float Z = 0.f;
    #pragma unroll
    for (int a = 0; a <= 4; ++a)
        #pragma unroll
        for (int b = 0; b <= 4 - a; ++b)
            #pragma unroll
            for (int c = 0; c <= 4 - a - b; ++c)
                Z = fmaf(coef[(a * 5 + b) * 5 + c], xp[a] * yp[b] * zp[c], Z);

    // noise = sqrt(2/1000) * (Z^2 - 1)/4
    const float noise = 0.04472135954999579f * (Z * Z - 1.f) * 0.25f;
    out[idx] = scale_p[0] * (Z + noise) + bias_p[0];
}

extern "C" void kernel_launch(void* const* d_in, const int* in_sizes, int n_in,
                              void* d_out, int out_size, void* d_ws, size_t ws_size,
                              hipStream_t stream) {
    const float* inputs  = (const float*)d_in[0];   // [B,2] f32
    const float* w_U     = (const float*)d_in[1];   // [6]
    const float* w_RXZX  = (const float*)d_in[2];   // [6,4,3]
    const float* scale_p = (const float*)d_in[3];   // [1]
    const float* bias_p  = (const float*)d_in[4];   // [1]
    float* out  = (float*)d_out;
    float* coef = (float*)d_ws;                     // 125 floats scratch

    const int B = in_sizes[0] / 2;

    precompute_coef<<<1, 256, 0, stream>>>(w_U, w_RXZX, coef);
    eval_poly<<<(B + 255) / 256, 256, 0, stream>>>(
        (const float2*)inputs, coef, scale_p, bias_p, out, B);
}

// Round 3
// 54.739 us; speedup vs baseline: 1.3554x; 1.3554x over previous
//
#include <hip/hip_runtime.h>
#include <math.h>

// ---------------------------------------------------------------------------
// Quantum circuit collapses analytically:
//   state = v^{tensor4},  v = (RZ(f0)RY(f1))[:,0]
//   Bloch vector of v: x = sin f1 cos f0, y = sin f1 sin f0, z = cos f1
//   Z_exp = Tr(M rho^{tensor4}),  M = W^dag Z0 W (batch-independent, 16x16)
//         = degree-4 polynomial in (x,y,z): 35 monomial coefficients.
// Kernel 1 computes the coefficients (1 block); kernel 2 evaluates per batch.
// Round-1 lesson: the serial tid==0 collapse used a runtime-indexed local
// array -> scratch memory -> 78us. Now fully parallel via LDS.
// ---------------------------------------------------------------------------

struct cpx { float re, im; };

__device__ __forceinline__ cpx cmul(cpx a, cpx b) {
    return { a.re * b.re - a.im * b.im, a.re * b.im + a.im * b.re };
}
__device__ __forceinline__ cpx cadd(cpx a, cpx b) { return { a.re + b.re, a.im + b.im }; }

__device__ __forceinline__ void mm2(const cpx A[2][2], const cpx B[2][2], cpx C[2][2]) {
    #pragma unroll
    for (int r = 0; r < 2; ++r)
        #pragma unroll
        for (int c = 0; c < 2; ++c)
            C[r][c] = cadd(cmul(A[r][0], B[0][c]), cmul(A[r][1], B[1][c]));
}

__global__ __launch_bounds__(256) void precompute_coef(
    const float* __restrict__ w_U, const float* __restrict__ w_RXZX,
    float* __restrict__ coef /* 125 floats, index (a*5+b)*5+c */)
{
    __shared__ cpx  Wb[2][16][16];  // ping-pong circuit unitary
    __shared__ cpx  M[16][16];      // W^dag Z0 W
    __shared__ float cp[256];       // Pauli-basis coefficients
    __shared__ int   mono[256];     // monomial index per Pauli string
    __shared__ float wU[6], wR[72]; // preloaded parameters

    const int tid = threadIdx.x;
    const int i = tid >> 4, j = tid & 15;   // (row, col) owned by this thread

    // ---- preload all params in one parallel round trip ----
    if (tid < 6)  wU[tid] = w_U[tid];
    if (tid < 72) wR[tid] = w_RXZX[tid];

    Wb[0][i][j] = { (i == j) ? 1.f : 0.f, 0.f };
    __syncthreads();

    // ISWAP_PAIRS = [(1,2),(1,3),(1,2),(1,3),(0,3),(0,2)]
    const int PP[6] = {1, 1, 1, 1, 0, 0};
    const int QQ[6] = {2, 3, 2, 3, 3, 2};

    int cur = 0;
    for (int l = 0; l < 6; ++l) {
        // ---- iSWAP(w_U[l]) on (p,q): mixes states where bits p,q differ ----
        {
            const int wp = 8 >> PP[l], wq = 8 >> QQ[l];
            const float t = wU[l];
            const float ct = cosf(t), st = sinf(t); // [[c, i s],[i s, c]] on {|01>,|10>}
            const int bp = (i & wp) ? 1 : 0, bq = (i & wq) ? 1 : 0;
            cpx val;
            if (bp != bq) {
                cpx a = Wb[cur][i][j], b = Wb[cur][i ^ (wp | wq)][j];
                val.re = ct * a.re - st * b.im;   // c*a + (i*st)*b
                val.im = ct * a.im + st * b.re;
            } else {
                val = Wb[cur][i][j];
            }
            Wb[cur ^ 1][i][j] = val;
            cur ^= 1;
            __syncthreads();
        }

        // ---- per-qubit RXZX(a,b,c) = RX(a) RZ(b) RX(c) ----
        for (int qb = 0; qb < 4; ++qb) {
            const float ta = wR[(l * 4 + qb) * 3 + 0];
            const float tb = wR[(l * 4 + qb) * 3 + 1];
            const float tc = wR[(l * 4 + qb) * 3 + 2];
            float sa, ca, sb, cb, sc, cc;
            sincosf(0.5f * ta, &sa, &ca);
            sincosf(0.5f * tb, &sb, &cb);
            sincosf(0.5f * tc, &sc, &cc);
            const cpx RXa[2][2] = { { {ca, 0.f}, {0.f, -sa} }, { {0.f, -sa}, {ca, 0.f} } };
            const cpx RZb[2][2] = { { {cb, -sb}, {0.f, 0.f} }, { {0.f, 0.f}, {cb, sb} } };
            const cpx RXc[2][2] = { { {cc, 0.f}, {0.f, -sc} }, { {0.f, -sc}, {cc, 0.f} } };
            cpx T1[2][2], g[2][2];
            mm2(RZb, RXc, T1);
            mm2(RXa, T1, g);

            const int w = 8 >> qb;
            const int b = (i & w) ? 1 : 0;
            cpx x0 = Wb[cur][i & ~w][j], x1 = Wb[cur][i | w][j];
            cpx v2 = cadd(cmul(g[b][0], x0), cmul(g[b][1], x1));
            Wb[cur ^ 1][i][j] = v2;
            cur ^= 1;
            __syncthreads();
        }
    }

    // ---- M[i][j] = sum_k conj(W[k][i]) * z_k * W[k][j],  z_k = +1 (k<8) else -1
    cpx m = {0.f, 0.f};
    #pragma unroll
    for (int k = 0; k < 16; ++k) {
        const float zk = (k < 8) ? 1.f : -1.f;
        cpx a = Wb[cur][k][i];
        cpx b = Wb[cur][k][j];
        m.re += zk * (a.re * b.re + a.im * b.im);   // conj(a)*b
        m.im += zk * (a.re * b.im - a.im * b.re);
    }
    M[i][j] = m;
    __syncthreads();

    // ---- Pauli coefficient c_p = Tr(M * P_p)/16, p = tid.
    // Each Pauli column has exactly one nonzero: sum_col M[col][row(col)]*val(col)
    cpx acc = {0.f, 0.f};
    for (int col = 0; col < 16; ++col) {
        int row = 0;
        cpx val = {1.f, 0.f};
        #pragma unroll
        for (int k = 0; k < 4; ++k) {
            const int pk = (tid >> (6 - 2 * k)) & 3;   // 0=I,1=X,2=Y,3=Z
            const int b = (col >> (3 - k)) & 1;
            int rb = b;
            if (pk == 1) {
                rb = b ^ 1;
            } else if (pk == 2) {
                rb = b ^ 1;
                cpx f = {0.f, b ? -1.f : 1.f};   // sy[1][0]=i, sy[0][1]=-i
                val = cmul(val, f);
            } else if (pk == 3) {
                if (b) { val.re = -val.re; val.im = -val.im; }
            }
            row |= rb << (3 - k);
        }
        acc = cadd(acc, cmul(M[col][row], val));
    }
    cp[tid] = acc.re * (1.f / 16.f);   // Hermitian => trace real

    // monomial index of this thread's Pauli string (counts are order-invariant)
    {
        int a = 0, b = 0, c = 0;
        #pragma unroll
        for (int k = 0; k < 4; ++k) {
            const int pk = (tid >> (2 * k)) & 3;
            a += (pk == 1); b += (pk == 2); c += (pk == 3);
        }
        mono[tid] = (a * 5 + b) * 5 + c;
    }
    __syncthreads();

    // ---- parallel collapse: thread t sums all Pauli terms with mono==t ----
    if (tid < 125) {
        float s = 0.f;
        for (int p = 0; p < 256; ++p)          // ascending p: deterministic
            if (mono[p] == tid) s += cp[p];
        coef[tid] = s;
    }
}

__global__ __launch_bounds__(256) void eval_poly(
    const float4* __restrict__ in, const float* __restrict__ coef,
    const float* __restrict__ scale_p, const float* __restrict__ bias_p,
    float2* __restrict__ out, int B2)
{
    const int idx = blockIdx.x * blockDim.x + threadIdx.x;
    if (idx >= B2) return;

    const float4 f = in[idx];            // two elements: (f.x,f.y), (f.z,f.w)
    const float scale = scale_p[0], bias = bias_p[0];

    float2 res;
    #pragma unroll
    for (int e = 0; e < 2; ++e) {
        const float f0 = e ? f.z : f.x;
        const float f1 = e ? f.w : f.y;
        float s0, c0, s1, c1;
        sincosf(f0, &s0, &c0);
        sincosf(f1, &s1, &c1);
        const float x = s1 * c0, y = s1 * s0, z = c1;

        float xp[5], yp[5], zp[5];
        xp[0] = yp[0] = zp[0] = 1.f;
        #pragma unroll
        for (int k = 1; k < 5; ++k) {
            xp[k] = xp[k - 1] * x;
            yp[k] = yp[k - 1] * y;
            zp[k] = zp[k - 1] * z;
        }

        float Z = 0.f;
        #pragma unroll
        for (int a = 0; a <= 4; ++a)
            #pragma unroll
            for (int b = 0; b <= 4 - a; ++b)
                #pragma unroll
                for (int c = 0; c <= 4 - a - b; ++c)
                    Z = fmaf(coef[(a * 5 + b) * 5 + c], xp[a] * yp[b] * zp[c], Z);

        // noise = sqrt(2/1000) * (Z^2 - 1)/4
        const float noise = 0.04472135954999579f * (Z * Z - 1.f) * 0.25f;
        const float v = scale * (Z + noise) + bias;
        if (e) res.y = v; else res.x = v;
    }
    out[idx] = res;
}

extern "C" void kernel_launch(void* const* d_in, const int* in_sizes, int n_in,
                              void* d_out, int out_size, void* d_ws, size_t ws_size,
                              hipStream_t stream) {
    const float* inputs  = (const float*)d_in[0];   // [B,2] f32
    const float* w_U     = (const float*)d_in[1];   // [6]
    const float* w_RXZX  = (const float*)d_in[2];   // [6,4,3]
    const float* scale_p = (const float*)d_in[3];   // [1]
    const float* bias_p  = (const float*)d_in[4];   // [1]
    float* out  = (float*)d_out;
    float* coef = (float*)d_ws;                     // 125 floats scratch

    const int B = in_sizes[0] / 2;
    const int B2 = B / 2;                           // 2 elements per thread

    precompute_coef<<<1, 256, 0, stream>>>(w_U, w_RXZX, coef);
    eval_poly<<<(B2 + 255) / 256, 256, 0, stream>>>(
        (const float4*)inputs, coef, scale_p, bias_p, (float2*)out, B2);
}

// Round 4
// 41.443 us; speedup vs baseline: 1.7902x; 1.3208x over previous
//
#include <hip/hip_runtime.h>
#include <math.h>

// ---------------------------------------------------------------------------
// Quantum circuit collapses analytically:
//   state = v^{tensor4},  v = (RZ(f0)RY(f1))[:,0]
//   Bloch vector of v: x = sin f1 cos f0, y = sin f1 sin f0, z = cos f1
//   Z_exp = Tr(M rho^{tensor4}),  M = W^dag Z0 W (batch-independent, 16x16)
//         = degree-4 polynomial in (x,y,z): 35 monomial coefficients.
// Kernel 1 computes the coefficients (1 block); kernel 2 evaluates per batch.
// R1 lesson: runtime-indexed local arrays -> scratch -> latency serial chain.
// R3 lesson: same bug in the gate loop (g[b][*], PP[l]); gates now built ONCE
// in parallel into an LDS table, layer loop fully unrolled.
// ---------------------------------------------------------------------------

struct cpx { float re, im; };

__device__ __forceinline__ cpx cmul(cpx a, cpx b) {
    return { a.re * b.re - a.im * b.im, a.re * b.im + a.im * b.re };
}
__device__ __forceinline__ cpx cadd(cpx a, cpx b) { return { a.re + b.re, a.im + b.im }; }

__global__ __launch_bounds__(256) void precompute_coef(
    const float* __restrict__ w_U, const float* __restrict__ w_RXZX,
    float* __restrict__ coef /* 125 floats, index (a*5+b)*5+c */)
{
    __shared__ cpx   Wb[2][16][16];  // ping-pong circuit unitary
    __shared__ cpx   M[16][16];      // W^dag Z0 W
    __shared__ float cp[256];        // Pauli-basis coefficients
    __shared__ int   mono[256];      // monomial index per Pauli string
    __shared__ cpx   G[24][2][2];    // RXZX gate table (l*4+qb)
    __shared__ float ISc[6], ISs[6]; // iSWAP cos/sin

    const int tid = threadIdx.x;
    const int i = tid >> 4, j = tid & 15;   // (row, col) owned by this thread

    // ---- Phase A: build all gate matrices in parallel (no local arrays with
    //      runtime indices -> everything stays in registers) ----
    if (tid < 24) {
        const float ta = w_RXZX[tid * 3 + 0];
        const float tb = w_RXZX[tid * 3 + 1];
        const float tc = w_RXZX[tid * 3 + 2];
        float sa, ca, sb, cb, sc, cc;
        sincosf(0.5f * ta, &sa, &ca);
        sincosf(0.5f * tb, &sb, &cb);
        sincosf(0.5f * tc, &sc, &cc);
        // RX(t) = [[c, -i s],[-i s, c]],  RZ(t) = [[c - i s, 0],[0, c + i s]]
        // g = RX(a) @ RZ(b) @ RX(c); expand T = RZ(b)@RX(c) first.
        const cpx e0 = { cb, -sb };          // RZ diag 0
        const cpx e1 = { cb,  sb };          // RZ diag 1
        const cpx T00 = { e0.re * cc,            e0.im * cc };
        const cpx T01 = { e0.re * 0.f - e0.im * (-sc), e0.re * (-sc) + e0.im * 0.f };
        const cpx T10 = { -e1.im * (-sc), e1.re * (-sc) };
        const cpx T11 = { e1.re * cc,            e1.im * cc };
        // RX(a) rows: row0 = [ca, -i sa], row1 = [-i sa, ca]
        // g00 = ca*T00 + (-i sa)*T10 ; g01 = ca*T01 + (-i sa)*T11
        // g10 = (-i sa)*T00 + ca*T10 ; g11 = (-i sa)*T01 + ca*T11
        const cpx g00 = { ca * T00.re + sa * T10.im, ca * T00.im - sa * T10.re };
        const cpx g01 = { ca * T01.re + sa * T11.im, ca * T01.im - sa * T11.re };
        const cpx g10 = { sa * T00.im + ca * T10.re, -sa * T00.re + ca * T10.im };
        const cpx g11 = { sa * T01.im + ca * T11.re, -sa * T01.re + ca * T11.im };
        G[tid][0][0] = g00; G[tid][0][1] = g01;
        G[tid][1][0] = g10; G[tid][1][1] = g11;
    } else if (tid < 30) {
        const int l = tid - 24;
        const float t = w_U[l];
        ISc[l] = cosf(t);
        ISs[l] = sinf(t);
    }

    Wb[0][i][j] = { (i == j) ? 1.f : 0.f, 0.f };
    __syncthreads();

    // ISWAP_PAIRS = [(1,2),(1,3),(1,2),(1,3),(0,3),(0,2)]
    const int PP[6] = {1, 1, 1, 1, 0, 0};
    const int QQ[6] = {2, 3, 2, 3, 3, 2};

    int cur = 0;
    #pragma unroll
    for (int l = 0; l < 6; ++l) {
        // ---- iSWAP(w_U[l]) on (p,q): mixes states where bits p,q differ ----
        {
            const int wp = 8 >> PP[l], wq = 8 >> QQ[l];   // compile-time (unrolled)
            const float ct = ISc[l], st = ISs[l];
            const int bp = (i & wp) ? 1 : 0, bq = (i & wq) ? 1 : 0;
            cpx val;
            if (bp != bq) {
                cpx a = Wb[cur][i][j], b = Wb[cur][i ^ (wp | wq)][j];
                val.re = ct * a.re - st * b.im;   // c*a + (i*st)*b
                val.im = ct * a.im + st * b.re;
            } else {
                val = Wb[cur][i][j];
            }
            Wb[cur ^ 1][i][j] = val;
            cur ^= 1;
            __syncthreads();
        }

        // ---- per-qubit RXZX: gate entries read from LDS table ----
        #pragma unroll
        for (int qb = 0; qb < 4; ++qb) {
            const int gi = l * 4 + qb;
            const int w = 8 >> qb;
            const int b = (i & w) ? 1 : 0;
            const cpx g0 = G[gi][b][0];    // runtime b -> LDS addressing, fine
            const cpx g1 = G[gi][b][1];
            const cpx x0 = Wb[cur][i & ~w][j];
            const cpx x1 = Wb[cur][i | w][j];
            const cpx v2 = cadd(cmul(g0, x0), cmul(g1, x1));
            Wb[cur ^ 1][i][j] = v2;
            cur ^= 1;
            __syncthreads();
        }
    }

    // ---- M[i][j] = sum_k conj(W[k][i]) * z_k * W[k][j],  z_k = +1 (k<8) else -1
    cpx m = {0.f, 0.f};
    #pragma unroll
    for (int k = 0; k < 16; ++k) {
        const float zk = (k < 8) ? 1.f : -1.f;
        cpx a = Wb[cur][k][i];
        cpx b = Wb[cur][k][j];
        m.re += zk * (a.re * b.re + a.im * b.im);   // conj(a)*b
        m.im += zk * (a.re * b.im - a.im * b.re);
    }
    M[i][j] = m;
    __syncthreads();

    // ---- Pauli coefficient c_p = Tr(M * P_p)/16, p = tid.
    // Each Pauli column has exactly one nonzero: sum_col M[col][row(col)]*val(col)
    cpx acc = {0.f, 0.f};
    for (int col = 0; col < 16; ++col) {
        int row = 0;
        cpx val = {1.f, 0.f};
        #pragma unroll
        for (int k = 0; k < 4; ++k) {
            const int pk = (tid >> (6 - 2 * k)) & 3;   // 0=I,1=X,2=Y,3=Z
            const int b = (col >> (3 - k)) & 1;
            int rb = b;
            if (pk == 1) {
                rb = b ^ 1;
            } else if (pk == 2) {
                rb = b ^ 1;
                cpx f = {0.f, b ? -1.f : 1.f};   // sy[1][0]=i, sy[0][1]=-i
                val = cmul(val, f);
            } else if (pk == 3) {
                if (b) { val.re = -val.re; val.im = -val.im; }
            }
            row |= rb << (3 - k);
        }
        acc = cadd(acc, cmul(M[col][row], val));
    }
    cp[tid] = acc.re * (1.f / 16.f);   // Hermitian => trace real

    // monomial index of this thread's Pauli string (counts are order-invariant)
    {
        int a = 0, b = 0, c = 0;
        #pragma unroll
        for (int k = 0; k < 4; ++k) {
            const int pk = (tid >> (2 * k)) & 3;
            a += (pk == 1); b += (pk == 2); c += (pk == 3);
        }
        mono[tid] = (a * 5 + b) * 5 + c;
    }
    __syncthreads();

    // ---- parallel collapse: thread t sums all Pauli terms with mono==t ----
    if (tid < 125) {
        float s = 0.f;
        for (int p = 0; p < 256; ++p)          // ascending p: deterministic
            if (mono[p] == tid) s += cp[p];
        coef[tid] = s;
    }
}

__global__ __launch_bounds__(256) void eval_poly(
    const float4* __restrict__ in, const float* __restrict__ coef,
    const float* __restrict__ scale_p, const float* __restrict__ bias_p,
    float2* __restrict__ out, int B2)
{
    const int idx = blockIdx.x * blockDim.x + threadIdx.x;
    if (idx >= B2) return;

    const float4 f = in[idx];            // two elements: (f.x,f.y), (f.z,f.w)
    const float scale = scale_p[0], bias = bias_p[0];

    float2 res;
    #pragma unroll
    for (int e = 0; e < 2; ++e) {
        const float f0 = e ? f.z : f.x;
        const float f1 = e ? f.w : f.y;
        float s0, c0, s1, c1;
        sincosf(f0, &s0, &c0);
        sincosf(f1, &s1, &c1);
        const float x = s1 * c0, y = s1 * s0, z = c1;

        float xp[5], yp[5], zp[5];
        xp[0] = yp[0] = zp[0] = 1.f;
        #pragma unroll
        for (int k = 1; k < 5; ++k) {
            xp[k] = xp[k - 1] * x;
            yp[k] = yp[k - 1] * y;
            zp[k] = zp[k - 1] * z;
        }

        float Z = 0.f;
        #pragma unroll
        for (int a = 0; a <= 4; ++a)
            #pragma unroll
            for (int b = 0; b <= 4 - a; ++b)
                #pragma unroll
                for (int c = 0; c <= 4 - a - b; ++c)
                    Z = fmaf(coef[(a * 5 + b) * 5 + c], xp[a] * yp[b] * zp[c], Z);

        // noise = sqrt(2/1000) * (Z^2 - 1)/4
        const float noise = 0.04472135954999579f * (Z * Z - 1.f) * 0.25f;
        const float v = scale * (Z + noise) + bias;
        if (e) res.y = v; else res.x = v;
    }
    out[idx] = res;
}

extern "C" void kernel_launch(void* const* d_in, const int* in_sizes, int n_in,
                              void* d_out, int out_size, void* d_ws, size_t ws_size,
                              hipStream_t stream) {
    const float* inputs  = (const float*)d_in[0];   // [B,2] f32
    const float* w_U     = (const float*)d_in[1];   // [6]
    const float* w_RXZX  = (const float*)d_in[2];   // [6,4,3]
    const float* scale_p = (const float*)d_in[3];   // [1]
    const float* bias_p  = (const float*)d_in[4];   // [1]
    float* out  = (float*)d_out;
    float* coef = (float*)d_ws;                     // 125 floats scratch

    const int B = in_sizes[0] / 2;
    const int B2 = B / 2;                           // 2 elements per thread

    precompute_coef<<<1, 256, 0, stream>>>(w_U, w_RXZX, coef);
    eval_poly<<<(B2 + 255) / 256, 256, 0, stream>>>(
        (const float4*)inputs, coef, scale_p, bias_p, (float2*)out, B2);
}

// Round 5
// 27.622 us; speedup vs baseline: 2.6859x; 1.5003x over previous
//
#include <hip/hip_runtime.h>
#include <math.h>

// ---------------------------------------------------------------------------
// Quantum circuit collapses analytically:
//   state = v^{tensor4},  v = (RZ(f0)RY(f1))[:,0]
//   Bloch vector of v: x = sin f1 cos f0, y = sin f1 sin f0, z = cos f1
//   Z_exp = Tr(M rho^{tensor4}),  M = W^dag Z0 W (batch-independent, 16x16)
//         = degree-4 polynomial in (x,y,z): 35 monomial coefficients.
// R1: runtime-indexed local arrays -> scratch -> 78us.
// R3: same bug in gate loop; gates to LDS table -> 48us.
// R4: still latency-bound (35us): 30 LDS round-trip stages + unpipelined
//     collapse loop. Now: layers fused to 4x4 gates (12 stages), arithmetic
//     monomial index + uniform pipelined reads in collapse, unrolled trace.
// ---------------------------------------------------------------------------

struct cpx { float re, im; };

__device__ __forceinline__ cpx cmul(cpx a, cpx b) {
    return { a.re * b.re - a.im * b.im, a.re * b.im + a.im * b.re };
}
__device__ __forceinline__ cpx cadd(cpx a, cpx b) { return { a.re + b.re, a.im + b.im }; }

__global__ __launch_bounds__(256) void precompute_coef(
    const float* __restrict__ w_U, const float* __restrict__ w_RXZX,
    float* __restrict__ coef /* 125 floats, index (a*5+b)*5+c */)
{
    __shared__ cpx   Wb[2][16][16];  // ping-pong circuit unitary
    __shared__ cpx   M[16][16];      // W^dag Z0 W
    __shared__ float cp[256];        // Pauli-basis coefficients
    __shared__ cpx   R[24][2][2];    // RXZX 2x2 gate table (l*4+qb)
    __shared__ cpx   LM[12][4][4];   // fused 4x4 layer matrices (2 per layer)
    __shared__ float ISc[6], ISs[6]; // iSWAP cos/sin

    const int tid = threadIdx.x;
    const int i = tid >> 4, j = tid & 15;   // (row, col) owned by this thread

    // ---- Phase A1: 2x2 RXZX gates + iSWAP params (all compile-time local idx)
    if (tid < 24) {
        const float ta = w_RXZX[tid * 3 + 0];
        const float tb = w_RXZX[tid * 3 + 1];
        const float tc = w_RXZX[tid * 3 + 2];
        float sa, ca, sb, cb, sc, cc;
        sincosf(0.5f * ta, &sa, &ca);
        sincosf(0.5f * tb, &sb, &cb);
        sincosf(0.5f * tc, &sc, &cc);
        // RX(t)=[[c,-is],[-is,c]], RZ(t)=diag(c-is, c+is); g = RX(a)RZ(b)RX(c)
        const cpx e0 = { cb, -sb };
        const cpx e1 = { cb,  sb };
        const cpx T00 = { e0.re * cc, e0.im * cc };
        const cpx T01 = { -e0.im * (-sc), e0.re * (-sc) };
        const cpx T10 = { -e1.im * (-sc), e1.re * (-sc) };
        const cpx T11 = { e1.re * cc, e1.im * cc };
        const cpx g00 = { ca * T00.re + sa * T10.im, ca * T00.im - sa * T10.re };
        const cpx g01 = { ca * T01.re + sa * T11.im, ca * T01.im - sa * T11.re };
        const cpx g10 = { sa * T00.im + ca * T10.re, -sa * T00.re + ca * T10.im };
        const cpx g11 = { sa * T01.im + ca * T11.re, -sa * T01.re + ca * T11.im };
        R[tid][0][0] = g00; R[tid][0][1] = g01;
        R[tid][1][0] = g10; R[tid][1][1] = g11;
    } else if (tid < 30) {
        const int l = tid - 24;
        const float t = w_U[l];
        ISc[l] = cosf(t);
        ISs[l] = sinf(t);
    }
    Wb[0][i][j] = { (i == j) ? 1.f : 0.f, 0.f };
    __syncthreads();

    // ---- Phase A2: fused 4x4 layer matrices, one entry per thread (192 thr)
    // Layer l byte in PAIR: p | q<<2 | r<<4 | s<<6 (pairs (p,q) iSWAP'd,
    // (r,s) the complement). PAIRS=[(1,2),(1,3),(1,2),(1,3),(0,3),(0,2)].
    if (tid < 192) {
        const int m = tid >> 4, e = tid & 15, u = e >> 2, w = e & 3;
        const int l = m >> 1;
        const unsigned long long PAIR = 0xD89C8DC98DC9ULL;
        const int code = (int)((PAIR >> (8 * l)) & 0xFF);
        const int sh = (m & 1) ? 4 : 0;
        const int qa  = (code >> sh) & 3;
        const int qb2 = (code >> (sh + 2)) & 3;
        const int ra = l * 4 + qa, rb = l * 4 + qb2;
        cpx res;
        if (m & 1) {
            // B = R_r (x) R_s : entry = Rr[u1][w1] * Rs[u0][w0]
            res = cmul(R[ra][u >> 1][w >> 1], R[rb][u & 1][w & 1]);
        } else {
            // A = (R_p (x) R_q) * iSWAP;  iSWAP cols: 0->k0, 3->k3,
            // 1-> c*k1 + is*k2, 2-> is*k1 + c*k2
            if (w == 0)      res = cmul(R[ra][u >> 1][0], R[rb][u & 1][0]);
            else if (w == 3) res = cmul(R[ra][u >> 1][1], R[rb][u & 1][1]);
            else {
                const cpx k1 = cmul(R[ra][u >> 1][0], R[rb][u & 1][1]);
                const cpx k2 = cmul(R[ra][u >> 1][1], R[rb][u & 1][0]);
                const cpx tc = (w == 1) ? k1 : k2;  // * c
                const cpx ts = (w == 1) ? k2 : k1;  // * i s
                const float c = ISc[l], s = ISs[l];
                res.re = c * tc.re - s * ts.im;
                res.im = c * tc.im + s * ts.re;
            }
        }
        LM[m][u][w] = res;
    }
    __syncthreads();

    // ---- Sweep: 12 fused stages (A then B per layer; disjoint qubits commute)
    constexpr int QA[12] = {1,0, 1,0, 1,0, 1,0, 0,1, 0,1};
    constexpr int QB[12] = {2,3, 3,2, 2,3, 3,2, 3,2, 2,3};
    int cur = 0;
    #pragma unroll
    for (int s = 0; s < 12; ++s) {
        const int qa = QA[s], qb2 = QB[s];            // compile-time
        const int wa = 8 >> qa, wb = 8 >> qb2;
        const int u = (((i >> (3 - qa)) & 1) << 1) | ((i >> (3 - qb2)) & 1);
        const int base = i & ~(wa | wb);
        const cpx g0 = LM[s][u][0], g1 = LM[s][u][1];
        const cpx g2 = LM[s][u][2], g3 = LM[s][u][3];
        const cpx x0 = Wb[cur][base][j];
        const cpx x1 = Wb[cur][base | wb][j];
        const cpx x2 = Wb[cur][base | wa][j];
        const cpx x3 = Wb[cur][base | wa | wb][j];
        cpx v;
        v.re = g0.re * x0.re - g0.im * x0.im + g1.re * x1.re - g1.im * x1.im
             + g2.re * x2.re - g2.im * x2.im + g3.re * x3.re - g3.im * x3.im;
        v.im = g0.re * x0.im + g0.im * x0.re + g1.re * x1.im + g1.im * x1.re
             + g2.re * x2.im + g2.im * x2.re + g3.re * x3.im + g3.im * x3.re;
        Wb[cur ^ 1][i][j] = v;
        cur ^= 1;
        __syncthreads();
    }
    // cur == 0 after 12 toggles

    // ---- M[i][j] = sum_k conj(W[k][i]) * z_k * W[k][j],  z_k = +1 (k<8) else -1
    cpx m = {0.f, 0.f};
    #pragma unroll
    for (int k = 0; k < 16; ++k) {
        const float zk = (k < 8) ? 1.f : -1.f;
        cpx a = Wb[cur][k][i];
        cpx b = Wb[cur][k][j];
        m.re += zk * (a.re * b.re + a.im * b.im);   // conj(a)*b
        m.im += zk * (a.re * b.im - a.im * b.re);
    }
    M[i][j] = m;
    __syncthreads();

    // ---- Pauli coefficient c_p = Tr(M * P_p)/16, p = tid (unrolled -> 16
    //      independent LDS reads, pipelined)
    cpx acc = {0.f, 0.f};
    #pragma unroll
    for (int col = 0; col < 16; ++col) {
        int row = 0;
        cpx val = {1.f, 0.f};
        #pragma unroll
        for (int k = 0; k < 4; ++k) {
            const int pk = (tid >> (6 - 2 * k)) & 3;   // 0=I,1=X,2=Y,3=Z
            const int b = (col >> (3 - k)) & 1;
            int rb = b;
            if (pk == 1) {
                rb = b ^ 1;
            } else if (pk == 2) {
                rb = b ^ 1;
                cpx f = {0.f, b ? -1.f : 1.f};   // sy[1][0]=i, sy[0][1]=-i
                val = cmul(val, f);
            } else if (pk == 3) {
                if (b) { val.re = -val.re; val.im = -val.im; }
            }
            row |= rb << (3 - k);
        }
        acc = cadd(acc, cmul(M[col][row], val));
    }
    cp[tid] = acc.re * (1.f / 16.f);   // Hermitian => trace real
    __syncthreads();

    // ---- parallel collapse: thread t sums Pauli terms whose exponent-count
    // monomial equals t. Index computed ARITHMETICALLY (no LDS mono table);
    // cp[p] reads are uniform-address broadcasts, unrolled -> pipelined.
    if (tid < 125) {
        float s = 0.f;
        #pragma unroll 8
        for (int p = 0; p < 256; ++p) {
            // 2-bit fields: 01 -> X, 10 -> Y, 11 -> Z
            const int lo = p & 0x55, hi = (p >> 1) & 0x55;
            const int a = __popc(lo & ~hi);
            const int b = __popc(hi & ~lo);
            const int c = __popc(lo & hi);
            const float v = cp[p];
            s += (((a * 5 + b) * 5 + c) == tid) ? v : 0.f;
        }
        coef[tid] = s;
    }
}

__global__ __launch_bounds__(256) void eval_poly(
    const float4* __restrict__ in, const float* __restrict__ coef,
    const float* __restrict__ scale_p, const float* __restrict__ bias_p,
    float2* __restrict__ out, int B2)
{
    const int idx = blockIdx.x * blockDim.x + threadIdx.x;
    if (idx >= B2) return;

    const float4 f = in[idx];            // two elements: (f.x,f.y), (f.z,f.w)
    const float scale = scale_p[0], bias = bias_p[0];

    float2 res;
    #pragma unroll
    for (int e = 0; e < 2; ++e) {
        const float f0 = e ? f.z : f.x;
        const float f1 = e ? f.w : f.y;
        float s0, c0, s1, c1;
        sincosf(f0, &s0, &c0);
        sincosf(f1, &s1, &c1);
        const float x = s1 * c0, y = s1 * s0, z = c1;

        float xp[5], yp[5], zp[5];
        xp[0] = yp[0] = zp[0] = 1.f;
        #pragma unroll
        for (int k = 1; k < 5; ++k) {
            xp[k] = xp[k - 1] * x;
            yp[k] = yp[k - 1] * y;
            zp[k] = zp[k - 1] * z;
        }

        float Z = 0.f;
        #pragma unroll
        for (int a = 0; a <= 4; ++a)
            #pragma unroll
            for (int b = 0; b <= 4 - a; ++b)
                #pragma unroll
                for (int c = 0; c <= 4 - a - b; ++c)
                    Z = fmaf(coef[(a * 5 + b) * 5 + c], xp[a] * yp[b] * zp[c], Z);

        // noise = sqrt(2/1000) * (Z^2 - 1)/4
        const float noise = 0.04472135954999579f * (Z * Z - 1.f) * 0.25f;
        const float v = scale * (Z + noise) + bias;
        if (e) res.y = v; else res.x = v;
    }
    out[idx] = res;
}

extern "C" void kernel_launch(void* const* d_in, const int* in_sizes, int n_in,
                              void* d_out, int out_size, void* d_ws, size_t ws_size,
                              hipStream_t stream) {
    const float* inputs  = (const float*)d_in[0];   // [B,2] f32
    const float* w_U     = (const float*)d_in[1];   // [6]
    const float* w_RXZX  = (const float*)d_in[2];   // [6,4,3]
    const float* scale_p = (const float*)d_in[3];   // [1]
    const float* bias_p  = (const float*)d_in[4];   // [1]
    float* out  = (float*)d_out;
    float* coef = (float*)d_ws;                     // 125 floats scratch

    const int B = in_sizes[0] / 2;
    const int B2 = B / 2;                           // 2 elements per thread

    precompute_coef<<<1, 256, 0, stream>>>(w_U, w_RXZX, coef);
    eval_poly<<<(B2 + 255) / 256, 256, 0, stream>>>(
        (const float4*)inputs, coef, scale_p, bias_p, (float2*)out, B2);
}